// Round 2
// baseline (744.852 us; speedup 1.0000x reference)
//
#include <hip/hip_runtime.h>

#define DIM 1024
#define NQ 6
#define NBLOCKS 2048

// One wave (64 lanes) per row; lane owns columns {j*256 + lane*4 .. +3}, j=0..3.
// Weights staged once per block: w1s[q][d] (row-major copy, 24KB) and
// w2t[q][d] (transpose of w2[d][q], 24KB). 48KB LDS -> 3 blocks/CU = 12 waves/CU.
// Row loop has NO barriers: wave-private folded butterfly (10 shuffles) +
// 6 fixed-lane broadcasts. Next row's x is prefetched before the reduction.
__global__ __launch_bounds__(256, 3) void ffq_wave_row(
    const float* __restrict__ x,
    const float* __restrict__ w1,
    const float* __restrict__ b1,
    const float* __restrict__ theta,
    const float* __restrict__ w2,
    const float* __restrict__ b2,
    float* __restrict__ out,
    int n_rows)
{
    __shared__ float w1s[NQ * DIM];
    __shared__ float w2t[NQ * DIM];

    const int t    = threadIdx.x;
    const int lane = t & 63;
    const int wave = t >> 6;
    const int c4   = lane * 4;

    // ---- stage weights into LDS (once per block) ----
    {
        const float4* src = reinterpret_cast<const float4*>(w1);
        float4*       dst = reinterpret_cast<float4*>(w1s);
        for (int i = t; i < NQ * DIM / 4; i += 256) dst[i] = src[i];
    }
    for (int d = t; d < DIM; d += 256) {
#pragma unroll
        for (int q = 0; q < NQ; ++q) w2t[q * DIM + d] = w2[d * NQ + q];
    }
    __syncthreads();  // the only barrier

    // ---- per-lane constants ----
    float b1f[NQ], ctf[NQ];
#pragma unroll
    for (int q = 0; q < NQ; ++q) { b1f[q] = b1[q]; ctf[q] = __cosf(theta[q]); }

    float4 b2v[4];
#pragma unroll
    for (int j = 0; j < 4; ++j)
        b2v[j] = *reinterpret_cast<const float4*>(b2 + j * 256 + c4);

    const int nwaves = NBLOCKS * 4;            // 8192 waves -> exactly 8 rows/wave
    int r = blockIdx.x * 4 + wave;

    float4 xv[4];
#pragma unroll
    for (int j = 0; j < 4; ++j) xv[j] = make_float4(0.f, 0.f, 0.f, 0.f);
    if (r < n_rows) {
#pragma unroll
        for (int j = 0; j < 4; ++j)
            xv[j] = *reinterpret_cast<const float4*>(x + (size_t)r * DIM + j * 256 + c4);
    }

    while (r < n_rows) {
        // prefetch next row (stays in flight across this row's compute)
        const int rn = r + nwaves;
        float4 xn[4];
#pragma unroll
        for (int j = 0; j < 4; ++j) xn[j] = make_float4(0.f, 0.f, 0.f, 0.f);
        if (rn < n_rows) {
#pragma unroll
            for (int j = 0; j < 4; ++j)
                xn[j] = *reinterpret_cast<const float4*>(x + (size_t)rn * DIM + j * 256 + c4);
        }

        // ---- proj partials: p[q] = sum over this lane's 16 columns ----
        float p[8];
#pragma unroll
        for (int q = 0; q < 8; ++q) p[q] = 0.f;
#pragma unroll
        for (int j = 0; j < 4; ++j) {
#pragma unroll
            for (int q = 0; q < NQ; ++q) {
                const float4 w = *reinterpret_cast<const float4*>(&w1s[q * DIM + j * 256 + c4]);
                p[q] = fmaf(xv[j].x, w.x,
                       fmaf(xv[j].y, w.y,
                       fmaf(xv[j].z, w.z,
                       fmaf(xv[j].w, w.w, p[q]))));
            }
        }

        // ---- folded butterfly: 8 values x 64 lanes -> lane holds total of value vperm ----
        float r4[4];
        {
            const bool up = (lane & 1) != 0;
#pragma unroll
            for (int i = 0; i < 4; ++i) {
                float send = up ? p[i] : p[i + 4];
                float keep = up ? p[i + 4] : p[i];
                r4[i] = keep + __shfl_xor(send, 1, 64);
            }
        }
        float r2[2];
        {
            const bool up = (lane & 2) != 0;
#pragma unroll
            for (int i = 0; i < 2; ++i) {
                float send = up ? r2[0] * 0.f + (up ? r4[i] : r4[i + 2]) : r4[i + 2];
                // (kept simple below)
                send = up ? r4[i] : r4[i + 2];
                float keep = up ? r4[i + 2] : r4[i];
                r2[i] = keep + __shfl_xor(send, 2, 64);
            }
        }
        float r1;
        {
            const bool up = (lane & 4) != 0;
            float send = up ? r2[0] : r2[1];
            float keep = up ? r2[1] : r2[0];
            r1 = keep + __shfl_xor(send, 4, 64);
        }
        r1 += __shfl_xor(r1, 8, 64);
        r1 += __shfl_xor(r1, 16, 64);
        r1 += __shfl_xor(r1, 32, 64);

        // value q resides in lane {0,4,2,6,1,5}; broadcast + activation
        float qv[NQ];
        {
            const float s0 = __shfl(r1, 0, 64);
            const float s1 = __shfl(r1, 4, 64);
            const float s2 = __shfl(r1, 2, 64);
            const float s3 = __shfl(r1, 6, 64);
            const float s4 = __shfl(r1, 1, 64);
            const float s5 = __shfl(r1, 5, 64);
            qv[0] = __cosf(s0 + b1f[0]) * ctf[0];
            qv[1] = __cosf(s1 + b1f[1]) * ctf[1];
            qv[2] = __cosf(s2 + b1f[2]) * ctf[2];
            qv[3] = __cosf(s3 + b1f[3]) * ctf[3];
            qv[4] = __cosf(s4 + b1f[4]) * ctf[4];
            qv[5] = __cosf(s5 + b1f[5]) * ctf[5];
        }

        // ---- expand: out = relu(q . w2^T + b2), 16 columns per lane ----
#pragma unroll
        for (int j = 0; j < 4; ++j) {
            float4 o = b2v[j];
#pragma unroll
            for (int q = 0; q < NQ; ++q) {
                const float4 w = *reinterpret_cast<const float4*>(&w2t[q * DIM + j * 256 + c4]);
                o.x = fmaf(qv[q], w.x, o.x);
                o.y = fmaf(qv[q], w.y, o.y);
                o.z = fmaf(qv[q], w.z, o.z);
                o.w = fmaf(qv[q], w.w, o.w);
            }
            o.x = fmaxf(o.x, 0.f); o.y = fmaxf(o.y, 0.f);
            o.z = fmaxf(o.z, 0.f); o.w = fmaxf(o.w, 0.f);
            *reinterpret_cast<float4*>(out + (size_t)r * DIM + j * 256 + c4) = o;
        }

#pragma unroll
        for (int j = 0; j < 4; ++j) xv[j] = xn[j];
        r = rn;
    }
}

extern "C" void kernel_launch(void* const* d_in, const int* in_sizes, int n_in,
                              void* d_out, int out_size, void* d_ws, size_t ws_size,
                              hipStream_t stream) {
    const float* x     = (const float*)d_in[0];
    const float* w1    = (const float*)d_in[1];
    const float* b1    = (const float*)d_in[2];
    const float* theta = (const float*)d_in[3];
    const float* w2    = (const float*)d_in[4];
    const float* b2    = (const float*)d_in[5];
    float* out = (float*)d_out;

    const int n_rows = in_sizes[0] / DIM;  // B*S = 65536
    ffq_wave_row<<<NBLOCKS, 256, 0, stream>>>(x, w1, b1, theta, w2, b2, out, n_rows);
}

// Round 3
// 447.665 us; speedup vs baseline: 1.6639x; 1.6639x over previous
//
#include <hip/hip_runtime.h>

#define DIM 1024
#define NQ 6
#define NBLOCKS 1024

// Block-per-row shape (proven clean HBM traffic in R0), 2 rows per iteration.
// Thread t owns cols d0=4t..4t+3. Per iteration:
//   prefetch next 2 rows (1 float4/thread/row = one 4KB instr per row)
//   -> 2x24 FMA partials -> 2 independent folded butterflies (interleaved)
//   -> 6 lanes/wave write partials red[row][q][wave] -> ONE barrier
//   -> broadcast float4 LDS reads (6/row) + cos -> 24 FMA expand + relu -> store.
// cos(theta) is pre-multiplied into the register w2 fragment.
__global__ __launch_bounds__(256, 4) void ffq2(
    const float* __restrict__ x,
    const float* __restrict__ w1,
    const float* __restrict__ b1,
    const float* __restrict__ theta,
    const float* __restrict__ w2,
    const float* __restrict__ b2,
    float* __restrict__ out,
    int n_rows)
{
    const int t    = threadIdx.x;
    const int lane = t & 63;
    const int wave = t >> 6;
    const int d0   = t * 4;

    // ---- register-cached weights ----
    float w1f[NQ][4];
#pragma unroll
    for (int q = 0; q < NQ; ++q) {
        float4 v = *reinterpret_cast<const float4*>(w1 + q * DIM + d0);
        w1f[q][0] = v.x; w1f[q][1] = v.y; w1f[q][2] = v.z; w1f[q][3] = v.w;
    }
    float b1f[NQ], ctf[NQ];
#pragma unroll
    for (int q = 0; q < NQ; ++q) { b1f[q] = b1[q]; ctf[q] = __cosf(theta[q]); }

    float w2f[4][NQ];  // w2f[i][q] = w2[(d0+i)*6+q] * cos(theta[q])
    {
        float flat[24];
        const float4* wp = reinterpret_cast<const float4*>(w2 + (size_t)d0 * NQ);
#pragma unroll
        for (int i = 0; i < 6; ++i) {
            float4 v = wp[i];
            flat[4 * i + 0] = v.x; flat[4 * i + 1] = v.y;
            flat[4 * i + 2] = v.z; flat[4 * i + 3] = v.w;
        }
#pragma unroll
        for (int i = 0; i < 4; ++i)
#pragma unroll
            for (int q = 0; q < NQ; ++q)
                w2f[i][q] = flat[i * NQ + q] * ctf[q];
    }
    const float4 b2v = *reinterpret_cast<const float4*>(b2 + d0);

    // lane's butterfly output value index (depends on lane&7 only)
    const int vperm = 4 * (lane & 1) + 2 * ((lane >> 1) & 1) + ((lane >> 2) & 1);

    __shared__ float red[2][2][NQ][4];  // [parity][row][q][wave] -- float4 over wave dim

    int i = blockIdx.x;
    int par = 0;

    float4 xv[2];
#pragma unroll
    for (int rr = 0; rr < 2; ++rr) xv[rr] = make_float4(0.f, 0.f, 0.f, 0.f);
    if (2 * i < n_rows) {
        xv[0] = *reinterpret_cast<const float4*>(x + (size_t)(2 * i) * DIM + d0);
        xv[1] = *reinterpret_cast<const float4*>(x + (size_t)(2 * i + 1) * DIM + d0);
    }

    while (2 * i < n_rows) {
        const int inext = i + NBLOCKS;
        float4 xn[2];
#pragma unroll
        for (int rr = 0; rr < 2; ++rr) xn[rr] = make_float4(0.f, 0.f, 0.f, 0.f);
        if (2 * inext < n_rows) {
            xn[0] = *reinterpret_cast<const float4*>(x + (size_t)(2 * inext) * DIM + d0);
            xn[1] = *reinterpret_cast<const float4*>(x + (size_t)(2 * inext + 1) * DIM + d0);
        }

        // ---- partial dots for both rows ----
        float p[2][8];
#pragma unroll
        for (int rr = 0; rr < 2; ++rr) {
#pragma unroll
            for (int q = 0; q < NQ; ++q)
                p[rr][q] = fmaf(xv[rr].x, w1f[q][0],
                           fmaf(xv[rr].y, w1f[q][1],
                           fmaf(xv[rr].z, w1f[q][2], xv[rr].w * w1f[q][3])));
            p[rr][6] = 0.f; p[rr][7] = 0.f;
        }

        // ---- two independent folded butterflies (interleaved by the compiler) ----
        float r1[2];
#pragma unroll
        for (int rr = 0; rr < 2; ++rr) {
            float r4[4];
            {
                const bool up = (lane & 1) != 0;
#pragma unroll
                for (int k = 0; k < 4; ++k) {
                    float send = up ? p[rr][k] : p[rr][k + 4];
                    float keep = up ? p[rr][k + 4] : p[rr][k];
                    r4[k] = keep + __shfl_xor(send, 1, 64);
                }
            }
            float r2[2];
            {
                const bool up = (lane & 2) != 0;
#pragma unroll
                for (int k = 0; k < 2; ++k) {
                    float send = up ? r4[k] : r4[k + 2];
                    float keep = up ? r4[k + 2] : r4[k];
                    r2[k] = keep + __shfl_xor(send, 2, 64);
                }
            }
            float v;
            {
                const bool up = (lane & 4) != 0;
                float send = up ? r2[0] : r2[1];
                float keep = up ? r2[1] : r2[0];
                v = keep + __shfl_xor(send, 4, 64);
            }
            v += __shfl_xor(v, 8, 64);
            v += __shfl_xor(v, 16, 64);
            v += __shfl_xor(v, 32, 64);
            r1[rr] = v;
        }

        if (lane < 8 && vperm < NQ) {
            red[par][0][vperm][wave] = r1[0];
            red[par][1][vperm][wave] = r1[1];
        }
        __syncthreads();

        // ---- combine wave partials (broadcast float4 reads), cos, expand, store ----
#pragma unroll
        for (int rr = 0; rr < 2; ++rr) {
            float qv[NQ];
#pragma unroll
            for (int q = 0; q < NQ; ++q) {
                float4 w4 = *reinterpret_cast<const float4*>(&red[par][rr][q][0]);
                float s = (w4.x + w4.y) + (w4.z + w4.w);
                qv[q] = __cosf(s + b1f[q]);
            }
            float4 o = b2v;
#pragma unroll
            for (int q = 0; q < NQ; ++q) {
                o.x = fmaf(qv[q], w2f[0][q], o.x);
                o.y = fmaf(qv[q], w2f[1][q], o.y);
                o.z = fmaf(qv[q], w2f[2][q], o.z);
                o.w = fmaf(qv[q], w2f[3][q], o.w);
            }
            o.x = fmaxf(o.x, 0.f); o.y = fmaxf(o.y, 0.f);
            o.z = fmaxf(o.z, 0.f); o.w = fmaxf(o.w, 0.f);
            *reinterpret_cast<float4*>(out + (size_t)(2 * i + rr) * DIM + d0) = o;
        }

        xv[0] = xn[0]; xv[1] = xn[1];
        i = inext;
        par ^= 1;
    }
}

extern "C" void kernel_launch(void* const* d_in, const int* in_sizes, int n_in,
                              void* d_out, int out_size, void* d_ws, size_t ws_size,
                              hipStream_t stream) {
    const float* x     = (const float*)d_in[0];
    const float* w1    = (const float*)d_in[1];
    const float* b1    = (const float*)d_in[2];
    const float* theta = (const float*)d_in[3];
    const float* w2    = (const float*)d_in[4];
    const float* b2    = (const float*)d_in[5];
    float* out = (float*)d_out;

    const int n_rows = in_sizes[0] / DIM;  // B*S = 65536
    ffq2<<<NBLOCKS, 256, 0, stream>>>(x, w1, b1, theta, w2, b2, out, n_rows);
}